// Round 1
// baseline (681.393 us; speedup 1.0000x reference)
//
#include <hip/hip_runtime.h>
#include <cstdint>
#include <cmath>

// Problem constants
#define B_   4
#define C_   512
#define HW_  4096
#define G_   32
#define CPG_ 16
#define EPS_ 1e-6f
#define SCALE_ 0.04419417382415922f  // 1/sqrt(512)

typedef __bf16 bf16_t;
typedef __bf16 bf16x8 __attribute__((ext_vector_type(8)));
typedef float  f32x4  __attribute__((ext_vector_type(4)));
typedef unsigned int u32;

// Async global->LDS copy, 16B per lane. LDS dest is wave-uniform base + lane*16.
__device__ __forceinline__ void cp16(const void* g, void* l) {
  __builtin_amdgcn_global_load_lds((__attribute__((address_space(1))) u32*)(g),
                                   (__attribute__((address_space(3))) u32*)(l),
                                   16, 0, 0);
}

__device__ __forceinline__ void zero_acc(f32x4 acc[4][4]) {
  f32x4 z = {0.f, 0.f, 0.f, 0.f};
#pragma unroll
  for (int i = 0; i < 4; ++i)
#pragma unroll
    for (int j = 0; j < 4; ++j) acc[i][j] = z;
}

// BT GEMM mainloop: C[m][n] = sum_k A[m][k] * B[n][k], both row-major (K contiguous).
// 128x128 tile, BK=32, 256 threads = 4 waves, each wave does a 64x64 subtile
// as 4x4 MFMA 16x16x32 bf16 tiles. A,B point at the tile's first row.
__device__ __forceinline__ void gemm_bt(const bf16_t* __restrict__ A,
                                        const bf16_t* __restrict__ B,
                                        int K, int lda, int ldb,
                                        f32x4 acc[4][4]) {
  __shared__ __align__(16) bf16_t As[128 * 32];
  __shared__ __align__(16) bf16_t Bs[128 * 32];
  const int tid  = threadIdx.x;
  const int wave = tid >> 6;
  const int lane = tid & 63;
  const int wm = (wave >> 1) * 64;
  const int wn = (wave & 1) * 64;
  // staging: wave stages rows [32*wave, 32*wave+32); lane covers row (lane>>2),
  // 16B chunk (lane&3). LDS offset == lane*16B (contiguous as HW requires).
  const int srow = lane >> 2;
  const int scol = (lane & 3) * 8;
  const bf16_t* gA = A + (size_t)(wave * 32 + srow) * lda + scol;
  const bf16_t* gB = B + (size_t)(wave * 32 + srow) * ldb + scol;
  bf16_t* lA = As + wave * 32 * 32;
  bf16_t* lB = Bs + wave * 32 * 32;
  const int fr = lane & 15;        // m (or n) within 16-tile
  const int fk = (lane >> 4) * 8;  // k offset within 32

  for (int k0 = 0; k0 < K; k0 += 32) {
    cp16(gA,                    lA);
    cp16(gA + (size_t)16 * lda, lA + 16 * 32);
    cp16(gB,                    lB);
    cp16(gB + (size_t)16 * ldb, lB + 16 * 32);
    gA += 32; gB += 32;
    __syncthreads();  // vmcnt(0) drain + barrier
    bf16x8 a[4], b[4];
#pragma unroll
    for (int i = 0; i < 4; ++i)
      a[i] = *(const bf16x8*)(As + (wm + i * 16 + fr) * 32 + fk);
#pragma unroll
    for (int j = 0; j < 4; ++j)
      b[j] = *(const bf16x8*)(Bs + (wn + j * 16 + fr) * 32 + fk);
#pragma unroll
    for (int i = 0; i < 4; ++i)
#pragma unroll
      for (int j = 0; j < 4; ++j)
        acc[i][j] = __builtin_amdgcn_mfma_f32_16x16x32_bf16(a[i], b[j], acc[i][j], 0, 0, 0);
    __syncthreads();
  }
}

// ---------------- small prep kernels ----------------

__global__ void __launch_bounds__(256) cast_w_kernel(const float* __restrict__ qkv_w,
                                                     const float* __restrict__ proj_w,
                                                     bf16_t* __restrict__ wqkv,
                                                     bf16_t* __restrict__ wproj) {
  int idx = blockIdx.x * 256 + threadIdx.x;
  const int nq = 1536 * 512;
  if (idx < nq) wqkv[idx] = (bf16_t)qkv_w[idx];
  else          wproj[idx - nq] = (bf16_t)proj_w[idx - nq];
}

__global__ void __launch_bounds__(256) gn_stats_kernel(const float* __restrict__ x,
                                                       float* __restrict__ stats) {
  __shared__ float rs[256], rss[256];
  const int bg = blockIdx.x;  // b*32+g; group occupies contiguous 65536 floats
  const float4* base = (const float4*)(x + (size_t)bg * (CPG_ * HW_));
  float s = 0.f, ss = 0.f;
  for (int i = threadIdx.x; i < CPG_ * HW_ / 4; i += 256) {
    float4 v = base[i];
    s  += v.x + v.y + v.z + v.w;
    ss += v.x * v.x + v.y * v.y + v.z * v.z + v.w * v.w;
  }
  rs[threadIdx.x] = s; rss[threadIdx.x] = ss;
  __syncthreads();
  for (int st = 128; st > 0; st >>= 1) {
    if ((int)threadIdx.x < st) {
      rs[threadIdx.x]  += rs[threadIdx.x + st];
      rss[threadIdx.x] += rss[threadIdx.x + st];
    }
    __syncthreads();
  }
  if (threadIdx.x == 0) {
    const float inv = 1.f / (float)(CPG_ * HW_);
    float mean = rs[0] * inv;
    float var  = rss[0] * inv - mean * mean;
    stats[bg * 2 + 0] = mean;
    stats[bg * 2 + 1] = rsqrtf(var + EPS_);
  }
}

// normalize + transpose: x[b][c][i] (fp32) -> xnT[b][i][c] (bf16)
__global__ void __launch_bounds__(256) norm_tr_kernel(const float* __restrict__ x,
                                                      const float* __restrict__ stats,
                                                      const float* __restrict__ nw,
                                                      const float* __restrict__ nb,
                                                      bf16_t* __restrict__ xnT) {
  __shared__ float tile[64][65];
  const int b  = blockIdx.z;
  const int i0 = blockIdx.x * 64;   // hw
  const int c0 = blockIdx.y * 64;   // channel
  const int tx = threadIdx.x & 63;
  const int ty = threadIdx.x >> 6;  // 0..3
  const int cbase = c0 + ty * 16;
  const int g = cbase >> 4;         // group const across r (16 channels per ty)
  const float mean = stats[(b * G_ + g) * 2 + 0];
  const float rstd = stats[(b * G_ + g) * 2 + 1];
#pragma unroll
  for (int r = 0; r < 16; ++r) {
    const int c = cbase + r;
    float v = x[((size_t)b * C_ + c) * HW_ + i0 + tx];
    tile[ty * 16 + r][tx] = (v - mean) * rstd * nw[c] + nb[c];
  }
  __syncthreads();
#pragma unroll
  for (int r = 0; r < 16; ++r) {
    const int il = ty * 16 + r;
    xnT[((size_t)b * HW_ + i0 + il) * C_ + c0 + tx] = (bf16_t)tile[tx][il];
  }
}

// ---------------- GEMM kernels ----------------

// QKt[b][i][o] = sum_c xnT[b][i][c] * wqkv[o][c] + qkv_b[o], o in [0,1024)
__global__ void __launch_bounds__(256) qk_gemm_kernel(const bf16_t* __restrict__ xnT,
                                                      const bf16_t* __restrict__ wqkv,
                                                      const float* __restrict__ qkv_b,
                                                      bf16_t* __restrict__ QKt) {
  const int b = blockIdx.z;
  f32x4 acc[4][4]; zero_acc(acc);
  const bf16_t* A  = xnT + ((size_t)b * HW_ + blockIdx.y * 128) * C_;
  const bf16_t* Bp = wqkv + (size_t)blockIdx.x * 128 * C_;
  gemm_bt(A, Bp, C_, C_, C_, acc);
  const int lane = threadIdx.x & 63, wave = threadIdx.x >> 6;
  const int wm = (wave >> 1) * 64, wn = (wave & 1) * 64;
  const int r0 = blockIdx.y * 128 + wm + ((lane >> 4) << 2);
  const int c0 = blockIdx.x * 128 + wn + (lane & 15);
#pragma unroll
  for (int i = 0; i < 4; ++i)
#pragma unroll
    for (int j = 0; j < 4; ++j) {
      const int col = c0 + j * 16;
      const float bias = qkv_b[col];
#pragma unroll
      for (int r = 0; r < 4; ++r) {
        const int row = r0 + i * 16 + r;
        QKt[((size_t)b * HW_ + row) * 1024 + col] = (bf16_t)(acc[i][j][r] + bias);
      }
    }
}

// V[b][c][i] = sum_k wqkv[1024+c][k] * xnT[b][i][k] + qkv_b[1024+c]
__global__ void __launch_bounds__(256) v_gemm_kernel(const bf16_t* __restrict__ wqkv,
                                                     const bf16_t* __restrict__ xnT,
                                                     const float* __restrict__ qkv_b,
                                                     bf16_t* __restrict__ V) {
  const int b = blockIdx.z;
  f32x4 acc[4][4]; zero_acc(acc);
  const bf16_t* A  = wqkv + (size_t)(1024 + blockIdx.y * 128) * C_;
  const bf16_t* Bp = xnT + ((size_t)b * HW_ + blockIdx.x * 128) * C_;
  gemm_bt(A, Bp, C_, C_, C_, acc);
  const int lane = threadIdx.x & 63, wave = threadIdx.x >> 6;
  const int wm = (wave >> 1) * 64, wn = (wave & 1) * 64;
  const int r0 = blockIdx.y * 128 + wm + ((lane >> 4) << 2);
  const int c0 = blockIdx.x * 128 + wn + (lane & 15);
#pragma unroll
  for (int i = 0; i < 4; ++i)
#pragma unroll
    for (int r = 0; r < 4; ++r) {
      const int row = r0 + i * 16 + r;
      const float bias = qkv_b[1024 + row];
#pragma unroll
      for (int j = 0; j < 4; ++j) {
        const int col = c0 + j * 16;
        V[((size_t)b * C_ + row) * HW_ + col] = (bf16_t)(acc[i][r0 ? j : j][r] + bias);
      }
    }
}

// P[i][j] = exp(scale * sum_c Q[i][c]*K[j][c]); lsum[i] += row partial sums (fp32)
__global__ void __launch_bounds__(256) sexp_gemm_kernel(const bf16_t* __restrict__ QKtb,
                                                        bf16_t* __restrict__ P,
                                                        float* __restrict__ lsum) {
  f32x4 acc[4][4]; zero_acc(acc);
  const bf16_t* A  = QKtb + (size_t)blockIdx.y * 128 * 1024;        // Q rows
  const bf16_t* Bp = QKtb + 512 + (size_t)blockIdx.x * 128 * 1024;  // K rows
  gemm_bt(A, Bp, 512, 1024, 1024, acc);
  const int lane = threadIdx.x & 63, wave = threadIdx.x >> 6;
  const int wm = (wave >> 1) * 64, wn = (wave & 1) * 64;
  const int r0 = blockIdx.y * 128 + wm + ((lane >> 4) << 2);
  const int c0 = blockIdx.x * 128 + wn + (lane & 15);
#pragma unroll
  for (int i = 0; i < 4; ++i)
#pragma unroll
    for (int r = 0; r < 4; ++r) {
      const int row = r0 + i * 16 + r;
      float part = 0.f;
#pragma unroll
      for (int j = 0; j < 4; ++j) {
        const int col = c0 + j * 16;
        float v = __expf(acc[i][j][r] * SCALE_);
        P[(size_t)row * HW_ + col] = (bf16_t)v;
        part += v;
      }
      part += __shfl_xor(part, 1);
      part += __shfl_xor(part, 2);
      part += __shfl_xor(part, 4);
      part += __shfl_xor(part, 8);
      if ((lane & 15) == 0) atomicAdd(&lsum[row], part);
    }
}

// hmT[i][c] = (sum_j P[i][j] * V[c][j]) / lsum[i]
__global__ void __launch_bounds__(256) pv_gemm_kernel(const bf16_t* __restrict__ P,
                                                      const bf16_t* __restrict__ Vb,
                                                      const float* __restrict__ lsum,
                                                      bf16_t* __restrict__ hmTb) {
  f32x4 acc[4][4]; zero_acc(acc);
  const bf16_t* A  = P + (size_t)blockIdx.y * 128 * HW_;
  const bf16_t* Bp = Vb + (size_t)blockIdx.x * 128 * HW_;
  gemm_bt(A, Bp, HW_, HW_, HW_, acc);
  const int lane = threadIdx.x & 63, wave = threadIdx.x >> 6;
  const int wm = (wave >> 1) * 64, wn = (wave & 1) * 64;
  const int r0 = blockIdx.y * 128 + wm + ((lane >> 4) << 2);
  const int c0 = blockIdx.x * 128 + wn + (lane & 15);
#pragma unroll
  for (int i = 0; i < 4; ++i)
#pragma unroll
    for (int r = 0; r < 4; ++r) {
      const int row = r0 + i * 16 + r;
      const float rl = 1.f / lsum[row];
#pragma unroll
      for (int j = 0; j < 4; ++j) {
        const int col = c0 + j * 16;
        hmTb[(size_t)row * C_ + col] = (bf16_t)(acc[i][j][r] * rl);
      }
    }
}

// out[b][o][i] = x[b][o][i] + proj_b[o] + sum_c wproj[o][c] * hmT[b][i][c]
__global__ void __launch_bounds__(256) proj_gemm_kernel(const bf16_t* __restrict__ wproj,
                                                        const bf16_t* __restrict__ hmT,
                                                        const float* __restrict__ proj_b,
                                                        const float* __restrict__ x,
                                                        float* __restrict__ out) {
  const int b = blockIdx.z;
  f32x4 acc[4][4]; zero_acc(acc);
  const bf16_t* A  = wproj + (size_t)blockIdx.y * 128 * C_;
  const bf16_t* Bp = hmT + ((size_t)b * HW_ + blockIdx.x * 128) * C_;
  gemm_bt(A, Bp, C_, C_, C_, acc);
  const int lane = threadIdx.x & 63, wave = threadIdx.x >> 6;
  const int wm = (wave >> 1) * 64, wn = (wave & 1) * 64;
  const int r0 = blockIdx.y * 128 + wm + ((lane >> 4) << 2);
  const int c0 = blockIdx.x * 128 + wn + (lane & 15);
#pragma unroll
  for (int i = 0; i < 4; ++i)
#pragma unroll
    for (int r = 0; r < 4; ++r) {
      const int row = r0 + i * 16 + r;
      const float bias = proj_b[row];
#pragma unroll
      for (int j = 0; j < 4; ++j) {
        const int col = c0 + j * 16;
        const size_t idx = ((size_t)b * C_ + row) * HW_ + col;
        out[idx] = x[idx] + bias + acc[i][j][r];
      }
    }
}

// ---------------- launch ----------------
// Workspace layout (bytes), total ~119.6 MB:
//   wqkv  bf16 [1536][512]            1,572,864
//   wproj bf16 [512][512]               524,288
//   stats f32  [128][2]                   1,024
//   xnT   bf16 [4][4096][512]        16,777,216
//   QKt   bf16 [4][4096][1024]       33,554,432
//   V     bf16 [4][512][4096]        16,777,216
//   hmT   bf16 [4][4096][512]        16,777,216
//   lsum  f32  [4096]                    16,384
//   P     bf16 [4096][4096]          33,554,432   (reused per batch)
extern "C" void kernel_launch(void* const* d_in, const int* in_sizes, int n_in,
                              void* d_out, int out_size, void* d_ws, size_t ws_size,
                              hipStream_t stream) {
  const float* x      = (const float*)d_in[0];
  const float* norm_w = (const float*)d_in[1];
  const float* norm_b = (const float*)d_in[2];
  const float* qkv_w  = (const float*)d_in[3];
  const float* qkv_b  = (const float*)d_in[4];
  const float* proj_w = (const float*)d_in[5];
  const float* proj_b = (const float*)d_in[6];
  float* out = (float*)d_out;

  char* ws = (char*)d_ws;
  size_t o = 0;
  bf16_t* wqkv  = (bf16_t*)(ws + o); o += (size_t)1536 * 512 * 2;
  bf16_t* wproj = (bf16_t*)(ws + o); o += (size_t)512 * 512 * 2;
  float*  stats = (float*)(ws + o);  o += 128 * 2 * 4;
  bf16_t* xnT   = (bf16_t*)(ws + o); o += (size_t)B_ * HW_ * C_ * 2;
  bf16_t* QKt   = (bf16_t*)(ws + o); o += (size_t)B_ * HW_ * 1024 * 2;
  bf16_t* Vbuf  = (bf16_t*)(ws + o); o += (size_t)B_ * C_ * HW_ * 2;
  bf16_t* hmT   = (bf16_t*)(ws + o); o += (size_t)B_ * HW_ * C_ * 2;
  float*  lsum  = (float*)(ws + o);  o += (size_t)HW_ * 4;
  bf16_t* P     = (bf16_t*)(ws + o); o += (size_t)HW_ * HW_ * 2;

  cast_w_kernel<<<4096, 256, 0, stream>>>(qkv_w, proj_w, wqkv, wproj);
  gn_stats_kernel<<<128, 256, 0, stream>>>(x, stats);
  norm_tr_kernel<<<dim3(HW_ / 64, C_ / 64, B_), 256, 0, stream>>>(x, stats, norm_w, norm_b, xnT);
  qk_gemm_kernel<<<dim3(1024 / 128, HW_ / 128, B_), 256, 0, stream>>>(xnT, wqkv, qkv_b, QKt);
  v_gemm_kernel<<<dim3(HW_ / 128, C_ / 128, B_), 256, 0, stream>>>(wqkv, xnT, qkv_b, Vbuf);
  for (int b = 0; b < B_; ++b) {
    hipMemsetAsync(lsum, 0, HW_ * sizeof(float), stream);
    sexp_gemm_kernel<<<dim3(HW_ / 128, HW_ / 128, 1), 256, 0, stream>>>(
        QKt + (size_t)b * HW_ * 1024, P, lsum);
    pv_gemm_kernel<<<dim3(C_ / 128, HW_ / 128, 1), 256, 0, stream>>>(
        P, Vbuf + (size_t)b * C_ * HW_, lsum, hmT + (size_t)b * HW_ * C_);
  }
  proj_gemm_kernel<<<dim3(HW_ / 128, C_ / 128, B_), 256, 0, stream>>>(
      wproj, hmT, proj_b, x, out);
}

// Round 2
// 442.069 us; speedup vs baseline: 1.5414x; 1.5414x over previous
//
#include <hip/hip_runtime.h>
#include <cstdint>
#include <cmath>

// Problem constants
#define B_   4
#define C_   512
#define HW_  4096
#define G_   32
#define CPG_ 16
#define EPS_ 1e-6f
#define SCALE_ 0.04419417382415922f  // 1/sqrt(512)

typedef __bf16 bf16_t;
typedef __bf16 bf16x8 __attribute__((ext_vector_type(8)));
typedef float  f32x4  __attribute__((ext_vector_type(4)));
typedef unsigned int u32;

// Async global->LDS copy, 16B per lane. LDS dest is wave-uniform base + lane*16.
__device__ __forceinline__ void cp16(const void* g, void* l) {
  __builtin_amdgcn_global_load_lds((__attribute__((address_space(1))) u32*)(g),
                                   (__attribute__((address_space(3))) u32*)(l),
                                   16, 0, 0);
}

__device__ __forceinline__ void zero_acc(f32x4 acc[4][4]) {
  f32x4 z = {0.f, 0.f, 0.f, 0.f};
#pragma unroll
  for (int i = 0; i < 4; ++i)
#pragma unroll
    for (int j = 0; j < 4; ++j) acc[i][j] = z;
}

// BT GEMM mainloop: C[m][n] = sum_k A[m][k] * B[n][k], both row-major (K contiguous).
// 128x128 tile, BK=32, 256 threads = 4 waves, each wave does a 64x64 subtile
// as 4x4 MFMA 16x16x32 bf16 tiles. A,B point at the tile's first row.
__device__ __forceinline__ void gemm_bt(const bf16_t* __restrict__ A,
                                        const bf16_t* __restrict__ B,
                                        int K, int lda, int ldb,
                                        f32x4 acc[4][4]) {
  __shared__ __align__(16) bf16_t As[128 * 32];
  __shared__ __align__(16) bf16_t Bs[128 * 32];
  const int tid  = threadIdx.x;
  const int wave = tid >> 6;
  const int lane = tid & 63;
  const int wm = (wave >> 1) * 64;
  const int wn = (wave & 1) * 64;
  // staging: wave stages rows [32*wave, 32*wave+32); lane covers row (lane>>2),
  // 16B chunk (lane&3). LDS offset == lane*16B (contiguous as HW requires).
  const int srow = lane >> 2;
  const int scol = (lane & 3) * 8;
  const bf16_t* gA = A + (size_t)(wave * 32 + srow) * lda + scol;
  const bf16_t* gB = B + (size_t)(wave * 32 + srow) * ldb + scol;
  bf16_t* lA = As + wave * 32 * 32;
  bf16_t* lB = Bs + wave * 32 * 32;
  const int fr = lane & 15;        // m (or n) within 16-tile
  const int fk = (lane >> 4) * 8;  // k offset within 32

  for (int k0 = 0; k0 < K; k0 += 32) {
    cp16(gA,                    lA);
    cp16(gA + (size_t)16 * lda, lA + 16 * 32);
    cp16(gB,                    lB);
    cp16(gB + (size_t)16 * ldb, lB + 16 * 32);
    gA += 32; gB += 32;
    __syncthreads();  // vmcnt(0) drain + barrier
    bf16x8 a[4], b[4];
#pragma unroll
    for (int i = 0; i < 4; ++i)
      a[i] = *(const bf16x8*)(As + (wm + i * 16 + fr) * 32 + fk);
#pragma unroll
    for (int j = 0; j < 4; ++j)
      b[j] = *(const bf16x8*)(Bs + (wn + j * 16 + fr) * 32 + fk);
#pragma unroll
    for (int i = 0; i < 4; ++i)
#pragma unroll
      for (int j = 0; j < 4; ++j)
        acc[i][j] = __builtin_amdgcn_mfma_f32_16x16x32_bf16(a[i], b[j], acc[i][j], 0, 0, 0);
    __syncthreads();
  }
}

// ---------------- small prep kernels ----------------

__global__ void __launch_bounds__(256) cast_w_kernel(const float* __restrict__ qkv_w,
                                                     const float* __restrict__ proj_w,
                                                     bf16_t* __restrict__ wqkv,
                                                     bf16_t* __restrict__ wproj) {
  int idx = blockIdx.x * 256 + threadIdx.x;
  const int nq = 1536 * 512;
  if (idx < nq) wqkv[idx] = (bf16_t)qkv_w[idx];
  else          wproj[idx - nq] = (bf16_t)proj_w[idx - nq];
}

__global__ void __launch_bounds__(256) gn_stats_kernel(const float* __restrict__ x,
                                                       float* __restrict__ stats) {
  __shared__ float rs[256], rss[256];
  const int bg = blockIdx.x;  // b*32+g; group occupies contiguous 65536 floats
  const float4* base = (const float4*)(x + (size_t)bg * (CPG_ * HW_));
  float s = 0.f, ss = 0.f;
  for (int i = threadIdx.x; i < CPG_ * HW_ / 4; i += 256) {
    float4 v = base[i];
    s  += v.x + v.y + v.z + v.w;
    ss += v.x * v.x + v.y * v.y + v.z * v.z + v.w * v.w;
  }
  rs[threadIdx.x] = s; rss[threadIdx.x] = ss;
  __syncthreads();
  for (int st = 128; st > 0; st >>= 1) {
    if ((int)threadIdx.x < st) {
      rs[threadIdx.x]  += rs[threadIdx.x + st];
      rss[threadIdx.x] += rss[threadIdx.x + st];
    }
    __syncthreads();
  }
  if (threadIdx.x == 0) {
    const float inv = 1.f / (float)(CPG_ * HW_);
    float mean = rs[0] * inv;
    float var  = rss[0] * inv - mean * mean;
    stats[bg * 2 + 0] = mean;
    stats[bg * 2 + 1] = rsqrtf(var + EPS_);
  }
}

// normalize + transpose: x[b][c][i] (fp32) -> xnT[b][i][c] (bf16)
__global__ void __launch_bounds__(256) norm_tr_kernel(const float* __restrict__ x,
                                                      const float* __restrict__ stats,
                                                      const float* __restrict__ nw,
                                                      const float* __restrict__ nb,
                                                      bf16_t* __restrict__ xnT) {
  __shared__ float tile[64][65];
  const int b  = blockIdx.z;
  const int i0 = blockIdx.x * 64;   // hw
  const int c0 = blockIdx.y * 64;   // channel
  const int tx = threadIdx.x & 63;
  const int ty = threadIdx.x >> 6;  // 0..3
  const int cbase = c0 + ty * 16;
  const int g = cbase >> 4;         // group const across r (16 channels per ty)
  const float mean = stats[(b * G_ + g) * 2 + 0];
  const float rstd = stats[(b * G_ + g) * 2 + 1];
#pragma unroll
  for (int r = 0; r < 16; ++r) {
    const int c = cbase + r;
    float v = x[((size_t)b * C_ + c) * HW_ + i0 + tx];
    tile[ty * 16 + r][tx] = (v - mean) * rstd * nw[c] + nb[c];
  }
  __syncthreads();
#pragma unroll
  for (int r = 0; r < 16; ++r) {
    const int il = ty * 16 + r;
    xnT[((size_t)b * HW_ + i0 + il) * C_ + c0 + tx] = (bf16_t)tile[tx][il];
  }
}

// ---------------- GEMM kernels ----------------

// QKt[b][i][o] = sum_c xnT[b][i][c] * wqkv[o][c] + qkv_b[o], o in [0,1024)
__global__ void __launch_bounds__(256) qk_gemm_kernel(const bf16_t* __restrict__ xnT,
                                                      const bf16_t* __restrict__ wqkv,
                                                      const float* __restrict__ qkv_b,
                                                      bf16_t* __restrict__ QKt) {
  const int b = blockIdx.z;
  f32x4 acc[4][4]; zero_acc(acc);
  const bf16_t* A  = xnT + ((size_t)b * HW_ + blockIdx.y * 128) * C_;
  const bf16_t* Bp = wqkv + (size_t)blockIdx.x * 128 * C_;
  gemm_bt(A, Bp, C_, C_, C_, acc);
  const int lane = threadIdx.x & 63, wave = threadIdx.x >> 6;
  const int wm = (wave >> 1) * 64, wn = (wave & 1) * 64;
  const int r0 = blockIdx.y * 128 + wm + ((lane >> 4) << 2);
  const int c0 = blockIdx.x * 128 + wn + (lane & 15);
#pragma unroll
  for (int i = 0; i < 4; ++i)
#pragma unroll
    for (int j = 0; j < 4; ++j) {
      const int col = c0 + j * 16;
      const float bias = qkv_b[col];
#pragma unroll
      for (int r = 0; r < 4; ++r) {
        const int row = r0 + i * 16 + r;
        QKt[((size_t)b * HW_ + row) * 1024 + col] = (bf16_t)(acc[i][j][r] + bias);
      }
    }
}

// V[b][c][i] = sum_k wqkv[1024+c][k] * xnT[b][i][k] + qkv_b[1024+c]
__global__ void __launch_bounds__(256) v_gemm_kernel(const bf16_t* __restrict__ wqkv,
                                                     const bf16_t* __restrict__ xnT,
                                                     const float* __restrict__ qkv_b,
                                                     bf16_t* __restrict__ V) {
  const int b = blockIdx.z;
  f32x4 acc[4][4]; zero_acc(acc);
  const bf16_t* A  = wqkv + (size_t)(1024 + blockIdx.y * 128) * C_;
  const bf16_t* Bp = xnT + ((size_t)b * HW_ + blockIdx.x * 128) * C_;
  gemm_bt(A, Bp, C_, C_, C_, acc);
  const int lane = threadIdx.x & 63, wave = threadIdx.x >> 6;
  const int wm = (wave >> 1) * 64, wn = (wave & 1) * 64;
  const int r0 = blockIdx.y * 128 + wm + ((lane >> 4) << 2);
  const int c0 = blockIdx.x * 128 + wn + (lane & 15);
#pragma unroll
  for (int i = 0; i < 4; ++i)
#pragma unroll
    for (int r = 0; r < 4; ++r) {
      const int row = r0 + i * 16 + r;
      const float bias = qkv_b[1024 + row];
#pragma unroll
      for (int j = 0; j < 4; ++j) {
        const int col = c0 + j * 16;
        V[((size_t)b * C_ + row) * HW_ + col] = (bf16_t)(acc[i][j][r] + bias);
      }
    }
}

// P[b][i][j] = exp(scale * sum_c Q[i][c]*K[j][c]); lsum[b][i] += row partial sums
__global__ void __launch_bounds__(256) sexp_gemm_kernel(const bf16_t* __restrict__ QKt,
                                                        bf16_t* __restrict__ P,
                                                        float* __restrict__ lsum) {
  const int b = blockIdx.z;
  const bf16_t* QKtb = QKt + (size_t)b * HW_ * 1024;
  bf16_t* Pb = P + (size_t)b * HW_ * HW_;
  float* lb = lsum + (size_t)b * HW_;
  f32x4 acc[4][4]; zero_acc(acc);
  const bf16_t* A  = QKtb + (size_t)blockIdx.y * 128 * 1024;        // Q rows
  const bf16_t* Bp = QKtb + 512 + (size_t)blockIdx.x * 128 * 1024;  // K rows
  gemm_bt(A, Bp, 512, 1024, 1024, acc);
  const int lane = threadIdx.x & 63, wave = threadIdx.x >> 6;
  const int wm = (wave >> 1) * 64, wn = (wave & 1) * 64;
  const int r0 = blockIdx.y * 128 + wm + ((lane >> 4) << 2);
  const int c0 = blockIdx.x * 128 + wn + (lane & 15);
#pragma unroll
  for (int i = 0; i < 4; ++i)
#pragma unroll
    for (int r = 0; r < 4; ++r) {
      const int row = r0 + i * 16 + r;
      float part = 0.f;
#pragma unroll
      for (int j = 0; j < 4; ++j) {
        const int col = c0 + j * 16;
        float v = __expf(acc[i][j][r] * SCALE_);
        Pb[(size_t)row * HW_ + col] = (bf16_t)v;
        part += v;
      }
      part += __shfl_xor(part, 1);
      part += __shfl_xor(part, 2);
      part += __shfl_xor(part, 4);
      part += __shfl_xor(part, 8);
      if ((lane & 15) == 0) atomicAdd(&lb[row], part);
    }
}

// hmT[b][i][c] = (sum_j P[b][i][j] * V[b][c][j]) / lsum[b][i]
__global__ void __launch_bounds__(256) pv_gemm_kernel(const bf16_t* __restrict__ P,
                                                      const bf16_t* __restrict__ V,
                                                      const float* __restrict__ lsum,
                                                      bf16_t* __restrict__ hmT) {
  const int b = blockIdx.z;
  const bf16_t* Pb = P + (size_t)b * HW_ * HW_;
  const bf16_t* Vb = V + (size_t)b * C_ * HW_;
  const float* lb = lsum + (size_t)b * HW_;
  bf16_t* hmTb = hmT + (size_t)b * HW_ * C_;
  f32x4 acc[4][4]; zero_acc(acc);
  const bf16_t* A  = Pb + (size_t)blockIdx.y * 128 * HW_;
  const bf16_t* Bp = Vb + (size_t)blockIdx.x * 128 * HW_;
  gemm_bt(A, Bp, HW_, HW_, HW_, acc);
  const int lane = threadIdx.x & 63, wave = threadIdx.x >> 6;
  const int wm = (wave >> 1) * 64, wn = (wave & 1) * 64;
  const int r0 = blockIdx.y * 128 + wm + ((lane >> 4) << 2);
  const int c0 = blockIdx.x * 128 + wn + (lane & 15);
#pragma unroll
  for (int i = 0; i < 4; ++i)
#pragma unroll
    for (int r = 0; r < 4; ++r) {
      const int row = r0 + i * 16 + r;
      const float rl = 1.f / lb[row];
#pragma unroll
      for (int j = 0; j < 4; ++j) {
        const int col = c0 + j * 16;
        hmTb[(size_t)row * C_ + col] = (bf16_t)(acc[i][j][r] * rl);
      }
    }
}

// out[b][o][i] = x[b][o][i] + proj_b[o] + sum_c wproj[o][c] * hmT[b][i][c]
__global__ void __launch_bounds__(256) proj_gemm_kernel(const bf16_t* __restrict__ wproj,
                                                        const bf16_t* __restrict__ hmT,
                                                        const float* __restrict__ proj_b,
                                                        const float* __restrict__ x,
                                                        float* __restrict__ out) {
  const int b = blockIdx.z;
  f32x4 acc[4][4]; zero_acc(acc);
  const bf16_t* A  = wproj + (size_t)blockIdx.y * 128 * C_;
  const bf16_t* Bp = hmT + ((size_t)b * HW_ + blockIdx.x * 128) * C_;
  gemm_bt(A, Bp, C_, C_, C_, acc);
  const int lane = threadIdx.x & 63, wave = threadIdx.x >> 6;
  const int wm = (wave >> 1) * 64, wn = (wave & 1) * 64;
  const int r0 = blockIdx.y * 128 + wm + ((lane >> 4) << 2);
  const int c0 = blockIdx.x * 128 + wn + (lane & 15);
#pragma unroll
  for (int i = 0; i < 4; ++i)
#pragma unroll
    for (int r = 0; r < 4; ++r) {
      const int row = r0 + i * 16 + r;
      const float bias = proj_b[row];
#pragma unroll
      for (int j = 0; j < 4; ++j) {
        const int col = c0 + j * 16;
        const size_t idx = ((size_t)b * C_ + row) * HW_ + col;
        out[idx] = x[idx] + bias + acc[i][j][r];
      }
    }
}

// ---------------- launch ----------------
// Workspace layout (bytes), total ~220.3 MB:
//   wqkv  bf16 [1536][512]            1,572,864
//   wproj bf16 [512][512]               524,288
//   stats f32  [128][2]                   1,024
//   xnT   bf16 [4][4096][512]        16,777,216
//   QKt   bf16 [4][4096][1024]       33,554,432
//   V     bf16 [4][512][4096]        16,777,216
//   hmT   bf16 [4][4096][512]        16,777,216
//   lsum  f32  [4][4096]                 65,536
//   P     bf16 [4][4096][4096]      134,217,728
extern "C" void kernel_launch(void* const* d_in, const int* in_sizes, int n_in,
                              void* d_out, int out_size, void* d_ws, size_t ws_size,
                              hipStream_t stream) {
  const float* x      = (const float*)d_in[0];
  const float* norm_w = (const float*)d_in[1];
  const float* norm_b = (const float*)d_in[2];
  const float* qkv_w  = (const float*)d_in[3];
  const float* qkv_b  = (const float*)d_in[4];
  const float* proj_w = (const float*)d_in[5];
  const float* proj_b = (const float*)d_in[6];
  float* out = (float*)d_out;

  char* ws = (char*)d_ws;
  size_t o = 0;
  bf16_t* wqkv  = (bf16_t*)(ws + o); o += (size_t)1536 * 512 * 2;
  bf16_t* wproj = (bf16_t*)(ws + o); o += (size_t)512 * 512 * 2;
  float*  stats = (float*)(ws + o);  o += 128 * 2 * 4;
  bf16_t* xnT   = (bf16_t*)(ws + o); o += (size_t)B_ * HW_ * C_ * 2;
  bf16_t* QKt   = (bf16_t*)(ws + o); o += (size_t)B_ * HW_ * 1024 * 2;
  bf16_t* Vbuf  = (bf16_t*)(ws + o); o += (size_t)B_ * C_ * HW_ * 2;
  bf16_t* hmT   = (bf16_t*)(ws + o); o += (size_t)B_ * HW_ * C_ * 2;
  float*  lsum  = (float*)(ws + o);  o += (size_t)B_ * HW_ * 4;
  bf16_t* P     = (bf16_t*)(ws + o); o += (size_t)B_ * HW_ * HW_ * 2;

  cast_w_kernel<<<4096, 256, 0, stream>>>(qkv_w, proj_w, wqkv, wproj);
  gn_stats_kernel<<<128, 256, 0, stream>>>(x, stats);
  hipMemsetAsync(lsum, 0, (size_t)B_ * HW_ * sizeof(float), stream);
  norm_tr_kernel<<<dim3(HW_ / 64, C_ / 64, B_), 256, 0, stream>>>(x, stats, norm_w, norm_b, xnT);
  qk_gemm_kernel<<<dim3(1024 / 128, HW_ / 128, B_), 256, 0, stream>>>(xnT, wqkv, qkv_b, QKt);
  v_gemm_kernel<<<dim3(HW_ / 128, C_ / 128, B_), 256, 0, stream>>>(wqkv, xnT, qkv_b, Vbuf);
  sexp_gemm_kernel<<<dim3(HW_ / 128, HW_ / 128, B_), 256, 0, stream>>>(QKt, P, lsum);
  pv_gemm_kernel<<<dim3(C_ / 128, HW_ / 128, B_), 256, 0, stream>>>(P, Vbuf, lsum, hmT);
  proj_gemm_kernel<<<dim3(HW_ / 128, C_ / 128, B_), 256, 0, stream>>>(
      wproj, hmT, proj_b, x, out);
}